// Round 22
// baseline (44.493 us; speedup 1.0000x reference)
//
#include <hip/hip_runtime.h>
#include <stdint.h>

#define NB 524288
#define NC 32
#define EPSV 1e-4f
#define DTB 0.12f      // DT * BETA
#define CLAMPV 3.0f
#define NSTEPS 4

typedef float f32x4 __attribute__((ext_vector_type(4)));
typedef short short8 __attribute__((ext_vector_type(8)));

union FragU { uint32_t u[4]; short8 s; uint4 q; };

__device__ __forceinline__ uint32_t pkbf16(float a, float b) {
    uint32_t r;
    asm("v_cvt_pk_bf16_f32 %0, %1, %2" : "=v"(r) : "v"(a), "v"(b));
    return r;   // low16 = bf16(a), high16 = bf16(b)
}
__device__ __forceinline__ float lo16f(uint32_t w) { return __uint_as_float(w << 16); }
__device__ __forceinline__ float hi16f(uint32_t w) { return __uint_as_float(w & 0xffff0000u); }
__device__ __forceinline__ float bfh(float v) { return lo16f(pkbf16(v, v)); } // RTN bf16 as f32

// 16x16x32 design, v2 (r21 mappings validated; numerics upgraded):
//   GEMM1 K-quadrants: q0: ch (pairs zh) | q1: ch (pairs zl) | q2: cl (pairs zh) | q3: cl (pairs zl)
//   -> FULL 4-term split in 2 independent MFMAs. bb term moved to fp32 elementwise (bbt table).
//   A1 tile t, row r hosts center c = (r>>2)*8 + t*4 + (r&3); lane(q,col) D1 reg j -> center q*8+(t*4)+j.
//   GEMM2: A2[row][k=center], rows 0-7 dims, 8-11 = dims 4-7 dup, 12-15 = dims 0-3 dup; 4-term split.
// ws: uint4 [0..63] A1t0 | [64..127] A1t1 | [128..191] A2h | [192..255] A2l
//     float [1024..1055] imtab: 1/mu^2[c] | float [1056..1087] bbtab: (|c|^2+eps)/mu^2[c]
__global__ void prep_kernel(const float* __restrict__ centers,
                            const float* __restrict__ mus,
                            uint4* __restrict__ wsu) {
    int t = threadIdx.x;
    if (t >= 64) return;
    int q = t >> 4, row = t & 15;

    // ---- A1 tiles: q0/q1 = c_hi, q2/q3 = c_lo ----
    #pragma unroll
    for (int tile = 0; tile < 2; ++tile) {
        int c = (row >> 2) * 8 + tile * 4 + (row & 3);
        float mu = mus[c];
        float im2 = 1.0f / (mu * mu);
        float vh[8], vl[8];
        #pragma unroll
        for (int d = 0; d < 8; ++d) {
            float v = -2.0f * centers[c * 8 + d] * im2;
            float h = bfh(v);
            vh[d] = h;
            vl[d] = v - h;
        }
        float e[8];
        #pragma unroll
        for (int i = 0; i < 8; ++i) e[i] = (q <= 1) ? vh[i] : vl[i];
        uint4 pk;
        pk.x = pkbf16(e[0], e[1]); pk.y = pkbf16(e[2], e[3]);
        pk.z = pkbf16(e[4], e[5]); pk.w = pkbf16(e[6], e[7]);
        wsu[tile * 64 + t] = pk;
    }

    // ---- A2 hi/lo ----
    {
        int d = (row < 8) ? row : (row < 12) ? (row - 4) : (row - 12);
        float eh[8], el[8];
        #pragma unroll
        for (int i = 0; i < 8; ++i) {
            int c = q * 8 + i;
            float mu = mus[c];
            float im2 = 1.0f / (mu * mu);
            float v = centers[c * 8 + d] * im2;
            float h = bfh(v);
            eh[i] = h;
            el[i] = v - h;
        }
        uint4 ph, pl;
        ph.x = pkbf16(eh[0], eh[1]); ph.y = pkbf16(eh[2], eh[3]);
        ph.z = pkbf16(eh[4], eh[5]); ph.w = pkbf16(eh[6], eh[7]);
        pl.x = pkbf16(el[0], el[1]); pl.y = pkbf16(el[2], el[3]);
        pl.z = pkbf16(el[4], el[5]); pl.w = pkbf16(el[6], el[7]);
        wsu[128 + t] = ph;
        wsu[192 + t] = pl;
    }

    // ---- imtab + bbtab (fp32-exact) ----
    if (t < 32) {
        float mu = mus[t];
        float im2 = 1.0f / (mu * mu);
        float bb = EPSV;
        #pragma unroll
        for (int d = 0; d < 8; ++d) {
            float cd = centers[t * 8 + d];
            bb = fmaf(cd, cd, bb);
        }
        ((float*)wsu)[1024 + t] = im2;
        ((float*)wsu)[1056 + t] = bb * im2;
    }
}

__global__ __launch_bounds__(256, 4) void pm_kernel(
    const float* __restrict__ z_in,
    const uint4* __restrict__ wsu,
    float* __restrict__ out)
{
    const int tid  = threadIdx.x;
    const int wid  = tid >> 6;
    const int lane = tid & 63;
    const int q    = lane >> 4;
    const int col  = lane & 15;
    const int point = blockIdx.x * 64 + wid * 16 + col;

    FragU A1a, A1b, A2hf, A2lf;
    A1a.q  = wsu[lane];        A1b.q  = wsu[64 + lane];
    A2hf.q = wsu[128 + lane];  A2lf.q = wsu[192 + lane];

    // per-lane tables, centers q*8+j (D1 reg order): imv = 1/mu^2, bbt = (|c|^2+eps)/mu^2
    const float* imt = ((const float*)wsu) + 1024 + q * 8;
    const float* bbp = ((const float*)wsu) + 1056 + q * 8;
    float imv[8], bbt[8];
    #pragma unroll
    for (int r = 0; r < 8; ++r) { imv[r] = imt[r]; bbt[r] = bbp[r]; }

    // all 4 quadrants hold full z (8 dims, fp32) for point col
    const float4* zp4 = (const float4*)z_in;
    float4 v0 = zp4[(size_t)point * 2];
    float4 v1 = zp4[(size_t)point * 2 + 1];
    float z0 = v0.x, z1 = v0.y, z2 = v0.z, z3 = v0.w;
    float z4 = v1.x, z5 = v1.y, z6 = v1.z, z7 = v1.w;

    const bool lowq = (q == 0) || (q == 3);   // this lane's D2 rows are dims 0-3
    const bool loz  = (q == 1) || (q == 3);   // this lane's B1 carries z_lo

    float zn0, zn1, zn2, zn3;

    #pragma unroll
    for (int s = 0; s < NSTEPS; ++s) {
        // zz = |z|^2 (fp32)
        float zz = z0 * z0;
        zz = fmaf(z1, z1, zz); zz = fmaf(z2, z2, zz); zz = fmaf(z3, z3, zz);
        zz = fmaf(z4, z4, zz); zz = fmaf(z5, z5, zz);
        zz = fmaf(z6, z6, zz); zz = fmaf(z7, z7, zz);

        // B1: q0/q2 = z_hi, q1/q3 = z_lo  (full 4-term split with A1's ch/ch/cl/cl)
        uint32_t h0 = pkbf16(z0, z1), h1 = pkbf16(z2, z3);
        uint32_t h2 = pkbf16(z4, z5), h3 = pkbf16(z6, z7);
        uint32_t l0 = pkbf16(z0 - lo16f(h0), z1 - hi16f(h0));
        uint32_t l1 = pkbf16(z2 - lo16f(h1), z3 - hi16f(h1));
        uint32_t l2 = pkbf16(z4 - lo16f(h2), z5 - hi16f(h2));
        uint32_t l3 = pkbf16(z6 - lo16f(h3), z7 - hi16f(h3));

        FragU B1;
        B1.u[0] = loz ? l0 : h0;
        B1.u[1] = loz ? l1 : h1;
        B1.u[2] = loz ? l2 : h2;
        B1.u[3] = loz ? l3 : h3;

        // GEMM1: 2 INDEPENDENT MFMAs -> D1 = -2 z.c / mu^2 (all 4 split terms in K)
        f32x4 D1a = {}, D1b = {};
        D1a = __builtin_amdgcn_mfma_f32_16x16x32_bf16(A1a.s, B1.s, D1a, 0, 0, 0);
        D1b = __builtin_amdgcn_mfma_f32_16x16x32_bf16(A1b.s, B1.s, D1b, 0, 0, 0);

        // r2' = D1 + zz/mu^2 + bb/mu^2 (both fp32) ; w = rsq = mu/r (8 per lane)
        float wv0 = __builtin_amdgcn_rsqf(fmaf(zz, imv[0], D1a[0] + bbt[0]));
        float wv1 = __builtin_amdgcn_rsqf(fmaf(zz, imv[1], D1a[1] + bbt[1]));
        float wv2 = __builtin_amdgcn_rsqf(fmaf(zz, imv[2], D1a[2] + bbt[2]));
        float wv3 = __builtin_amdgcn_rsqf(fmaf(zz, imv[3], D1a[3] + bbt[3]));
        float wv4 = __builtin_amdgcn_rsqf(fmaf(zz, imv[4], D1b[0] + bbt[4]));
        float wv5 = __builtin_amdgcn_rsqf(fmaf(zz, imv[5], D1b[1] + bbt[5]));
        float wv6 = __builtin_amdgcn_rsqf(fmaf(zz, imv[6], D1b[2] + bbt[6]));
        float wv7 = __builtin_amdgcn_rsqf(fmaf(zz, imv[7], D1b[3] + bbt[7]));

        // n partial (w = mu/r)
        float nl = ((wv0 + wv1) + (wv2 + wv3)) + ((wv4 + wv5) + (wv6 + wv7));

        // w^3 ; sw partial = sum w3/mu^2 (fp32)
        float w30 = (wv0 * wv0) * wv0, w31 = (wv1 * wv1) * wv1;
        float w32 = (wv2 * wv2) * wv2, w33 = (wv3 * wv3) * wv3;
        float w34 = (wv4 * wv4) * wv4, w35 = (wv5 * wv5) * wv5;
        float w36 = (wv6 * wv6) * wv6, w37 = (wv7 * wv7) * wv7;
        float m0 = w30 * imv[0], m1 = w31 * imv[1], m2 = w32 * imv[2], m3 = w33 * imv[3];
        float m4 = w34 * imv[4], m5 = w35 * imv[5], m6 = w36 * imv[6], m7 = w37 * imv[7];
        float sl = ((m0 + m1) + (m2 + m3)) + ((m4 + m5) + (m6 + m7));

        // cross-quadrant butterfly reduce (order-symmetric -> bitwise identical per col)
        float nsum = nl + __shfl_xor(nl, 16);
        nsum = nsum + __shfl_xor(nsum, 32);
        float ssum = sl + __shfl_xor(sl, 16);
        ssum = ssum + __shfl_xor(ssum, 32);

        // B2: local w3 (hi + lo residual), k = this lane's own centers
        FragU B2h, B2l;
        B2h.u[0] = pkbf16(w30, w31);
        B2l.u[0] = pkbf16(w30 - lo16f(B2h.u[0]), w31 - hi16f(B2h.u[0]));
        B2h.u[1] = pkbf16(w32, w33);
        B2l.u[1] = pkbf16(w32 - lo16f(B2h.u[1]), w33 - hi16f(B2h.u[1]));
        B2h.u[2] = pkbf16(w34, w35);
        B2l.u[2] = pkbf16(w34 - lo16f(B2h.u[2]), w35 - hi16f(B2h.u[2]));
        B2h.u[3] = pkbf16(w36, w37);
        B2l.u[3] = pkbf16(w36 - lo16f(B2h.u[3]), w37 - hi16f(B2h.u[3]));

        // GEMM2: full 4-term split, 4 dependent MFMAs
        f32x4 D2 = {};
        D2 = __builtin_amdgcn_mfma_f32_16x16x32_bf16(A2hf.s, B2h.s, D2, 0, 0, 0);
        D2 = __builtin_amdgcn_mfma_f32_16x16x32_bf16(A2lf.s, B2h.s, D2, 0, 0, 0);
        D2 = __builtin_amdgcn_mfma_f32_16x16x32_bf16(A2hf.s, B2l.s, D2, 0, 0, 0);
        D2 = __builtin_amdgcn_mfma_f32_16x16x32_bf16(A2lf.s, B2l.s, D2, 0, 0, 0);

        // epilogue: this lane updates its 4 dims
        float n = 1.0f + nsum;
        float sw = ssum;
        float scale = DTB * __builtin_amdgcn_rcpf(n);

        float zo0 = lowq ? z0 : z4;
        float zo1 = lowq ? z1 : z5;
        float zo2 = lowq ? z2 : z6;
        float zo3 = lowq ? z3 : z7;

        zn0 = fminf(fmaxf(fmaf(scale, fmaf(-sw, zo0, D2[0]), zo0), -CLAMPV), CLAMPV);
        zn1 = fminf(fmaxf(fmaf(scale, fmaf(-sw, zo1, D2[1]), zo1), -CLAMPV), CLAMPV);
        zn2 = fminf(fmaxf(fmaf(scale, fmaf(-sw, zo2, D2[2]), zo2), -CLAMPV), CLAMPV);
        zn3 = fminf(fmaxf(fmaf(scale, fmaf(-sw, zo3, D2[3]), zo3), -CLAMPV), CLAMPV);

        if (s != NSTEPS - 1) {
            // partner^16 holds the complementary 4 dims (bitwise-identical duplicates)
            float p0 = __shfl_xor(zn0, 16);
            float p1 = __shfl_xor(zn1, 16);
            float p2 = __shfl_xor(zn2, 16);
            float p3 = __shfl_xor(zn3, 16);
            z0 = lowq ? zn0 : p0;  z1 = lowq ? zn1 : p1;
            z2 = lowq ? zn2 : p2;  z3 = lowq ? zn3 : p3;
            z4 = lowq ? p0 : zn0;  z5 = lowq ? p1 : zn1;
            z6 = lowq ? p2 : zn2;  z7 = lowq ? p3 : zn3;
        }
    }

    float4* op = (float4*)out;
    if (q == 0) op[(size_t)point * 2]     = make_float4(zn0, zn1, zn2, zn3);
    if (q == 1) op[(size_t)point * 2 + 1] = make_float4(zn0, zn1, zn2, zn3);
}

extern "C" void kernel_launch(void* const* d_in, const int* in_sizes, int n_in,
                              void* d_out, int out_size, void* d_ws, size_t ws_size,
                              hipStream_t stream) {
    const float* z       = (const float*)d_in[0];
    const float* centers = (const float*)d_in[1];
    const float* mus     = (const float*)d_in[2];
    float* out           = (float*)d_out;
    uint4* wsu           = (uint4*)d_ws;

    prep_kernel<<<1, 64, 0, stream>>>(centers, mus, wsu);
    pm_kernel<<<NB / 64, 256, 0, stream>>>(z, wsu, out);   // 8192 blocks, 16 pts/wave
}

// Round 24
// 38.711 us; speedup vs baseline: 1.1493x; 1.1493x over previous
//
#include <hip/hip_runtime.h>
#include <stdint.h>

#define NB 524288
#define NC 32
#define EPSV 1e-4f
#define DTB 0.12f      // DT * BETA
#define CLAMPV 3.0f
#define NSTEPS 4

typedef float f32x16 __attribute__((ext_vector_type(16)));
typedef short short8 __attribute__((ext_vector_type(8)));

union FragU { uint32_t u[4]; short8 s; uint4 q; };

__device__ __forceinline__ uint32_t pkbf16(float a, float b) {
    uint32_t r;
    asm("v_cvt_pk_bf16_f32 %0, %1, %2" : "=v"(r) : "v"(a), "v"(b));
    return r;   // low16 = bf16(a), high16 = bf16(b)
}
__device__ __forceinline__ float lo16f(uint32_t w) { return __uint_as_float(w << 16); }
__device__ __forceinline__ float hi16f(uint32_t w) { return __uint_as_float(w & 0xffff0000u); }
__device__ __forceinline__ float bfh(float v) { return lo16f(pkbf16(v, v)); } // RTN bf16 as f32
__device__ __forceinline__ float sx32(float v) { return __shfl_xor(v, 32); }

// 32x32x16, k-embedded GEMM1 split (hi0 lanes feed k0-7, hi1 feed k8-15):
//   B1: hi0 = z_hi dims 0-7 | hi1 = z_lo dims 0-7 IN NATURAL DIM ORDER
//       (r23 BUG FIX: hi1 lane's za = dims 4-7, zb = dims 0-3 -> pack zb-residuals first)
//   A1f1 row c: k0-7 = ch, k8-15 = cl ; A1f2: k0-7 = cl, k8-15 = ch  (c-vec = -2c/mu^2)
//   D1 = f1*B1 + f2*B1 = full 4-term split. bb term in fp32 table (r22-validated).
// GEMM2: r14-exact fragments, split into two independent 4-chains (chunk0/chunk1), fp32 merge.
// ws layout:
//  uint4 [0..63]    A1f1 | [64..127] A1f2
//  uint4 [128..191] A2_hi chunk0 (k-permuted: center(ch,k) = ch*16 + (k&3)+8*((k>>2)&1)+4*(k>>3))
//  uint4 [192..255] A2_hi chunk1 | [256..319] A2_lo chunk0 | [320..383] A2_lo chunk1
//  float [1536..1567] imtab: 1/mu^2 of center crow(r,h)=(r&3)+8*(r>>2)+4*h
//  float [1568..1599] bbtab: (|c|^2+eps)/mu^2 of the same center (fp32-exact)
__global__ void prep_kernel(const float* __restrict__ centers,
                            const float* __restrict__ mus,
                            uint4* __restrict__ wsu) {
    int t = threadIdx.x;
    if (t >= 64) return;
    int row = t & 31, part = t >> 5;

    // ---- A1 fragments (k-embedded hi/lo split) ----
    {
        float mu = mus[row];
        float im2 = 1.0f / (mu * mu);
        float vh[8], vl[8];
        #pragma unroll
        for (int d = 0; d < 8; ++d) {
            float v = -2.0f * centers[row * 8 + d] * im2;
            float h = bfh(v);
            vh[d] = h;
            vl[d] = v - h;
        }
        uint4 f1, f2;
        const float* e1 = (part == 0) ? vh : vl;
        const float* e2 = (part == 0) ? vl : vh;
        f1.x = pkbf16(e1[0], e1[1]); f1.y = pkbf16(e1[2], e1[3]);
        f1.z = pkbf16(e1[4], e1[5]); f1.w = pkbf16(e1[6], e1[7]);
        f2.x = pkbf16(e2[0], e2[1]); f2.y = pkbf16(e2[2], e2[3]);
        f2.z = pkbf16(e2[4], e2[5]); f2.w = pkbf16(e2[6], e2[7]);
        wsu[t]      = f1;
        wsu[64 + t] = f2;
    }

    // ---- A2 (r14-exact: rows 0-7 = c_d/mu^2, row 8 = 1/mu^2; k-axis permuted) ----
    #pragma unroll
    for (int ch = 0; ch < 2; ++ch) {
        float v2[8];
        #pragma unroll
        for (int i = 0; i < 8; ++i) {
            int k = part * 8 + i;
            int within = (k & 3) + 8 * ((k >> 2) & 1) + 4 * (k >> 3);
            int ci = ch * 16 + within;
            float muc = mus[ci];
            float im2c = 1.0f / (muc * muc);
            v2[i] = (row < 8) ? (centers[ci * 8 + row] * im2c) : (row == 8) ? im2c : 0.0f;
        }
        uint32_t h2[4], l2[4];
        #pragma unroll
        for (int j = 0; j < 4; ++j) {
            float a = v2[2 * j], b = v2[2 * j + 1];
            h2[j] = pkbf16(a, b);
            l2[j] = pkbf16(a - lo16f(h2[j]), b - hi16f(h2[j]));
        }
        wsu[128 + ch * 64 + t] = make_uint4(h2[0], h2[1], h2[2], h2[3]);
        wsu[256 + ch * 64 + t] = make_uint4(l2[0], l2[1], l2[2], l2[3]);
    }

    // ---- imtab + bbtab (fp32-exact) ----
    if (t < 32) {
        int h2i = t >> 4, r = t & 15;
        int ci = (r & 3) + 8 * (r >> 2) + 4 * h2i;
        float muc = mus[ci];
        float im2c = 1.0f / (muc * muc);
        float bbc = EPSV;
        #pragma unroll
        for (int d = 0; d < 8; ++d) {
            float cd = centers[ci * 8 + d];
            bbc = fmaf(cd, cd, bbc);
        }
        ((float*)wsu)[1536 + t] = im2c;
        ((float*)wsu)[1568 + t] = bbc * im2c;
    }
}

__global__ __launch_bounds__(256, 4) void pm_kernel(
    const float* __restrict__ z_in,
    const uint4* __restrict__ wsu,
    float* __restrict__ out)
{
    const int tid  = threadIdx.x;
    const int wid  = tid >> 6;
    const int lane = tid & 63;
    const int hi   = lane >> 5;          // half-wave id
    const int col  = lane & 31;          // point within tile
    const int point = blockIdx.x * 128 + wid * 32 + col;

    // constant fragments (L2-resident)
    FragU A1f1, A1f2, A2h0, A2h1, A2l0, A2l1;
    A1f1.q = wsu[lane];        A1f2.q = wsu[64 + lane];
    A2h0.q = wsu[128 + lane];  A2h1.q = wsu[192 + lane];
    A2l0.q = wsu[256 + lane];  A2l1.q = wsu[320 + lane];

    // per-lane fp32 constants for centers crow(r,hi): imv = 1/mu^2, bbt = (|c|^2+eps)/mu^2
    const float* imt = ((const float*)wsu) + 1536 + hi * 16;
    const float* bbp = ((const float*)wsu) + 1568 + hi * 16;
    float imv[16], bbt[16];
    #pragma unroll
    for (int r = 0; r < 16; ++r) { imv[r] = imt[r]; bbt[r] = bbp[r]; }

    // z: this lane owns dims [hi*4 .. hi*4+3] (za); partner half via shfl (zb)
    const float4* zp4 = (const float4*)z_in;
    float4 hvec = zp4[(size_t)point * 2 + hi];
    float za0 = hvec.x, za1 = hvec.y, za2 = hvec.z, za3 = hvec.w;
    float zb0 = sx32(za0), zb1 = sx32(za1), zb2 = sx32(za2), zb3 = sx32(za3);

    #pragma unroll
    for (int s = 0; s < NSTEPS; ++s) {
        // zz = |z|^2 (fp32)
        float zz = za0 * za0;
        zz = fmaf(za1, za1, zz); zz = fmaf(za2, za2, zz); zz = fmaf(za3, za3, zz);
        zz = fmaf(zb0, zb0, zz); zz = fmaf(zb1, zb1, zz);
        zz = fmaf(zb2, zb2, zz); zz = fmaf(zb3, zb3, zz);

        // ---- B1 (single fragment), k-slots must be dims 0..7 in natural order ----
        // hi0 lane: za = dims 0-3, zb = dims 4-7 -> hi-parts in order h0,h1,h2,h3
        // hi1 lane: za = dims 4-7, zb = dims 0-3 -> lo-parts reordered l2,l3,l0,l1 (r23 fix)
        uint32_t h0 = pkbf16(za0, za1), h1 = pkbf16(za2, za3);
        uint32_t h2 = pkbf16(zb0, zb1), h3 = pkbf16(zb2, zb3);
        uint32_t l0 = pkbf16(za0 - lo16f(h0), za1 - hi16f(h0));
        uint32_t l1 = pkbf16(za2 - lo16f(h1), za3 - hi16f(h1));
        uint32_t l2 = pkbf16(zb0 - lo16f(h2), zb1 - hi16f(h2));
        uint32_t l3 = pkbf16(zb2 - lo16f(h3), zb3 - hi16f(h3));

        FragU B1;
        B1.u[0] = hi ? l2 : h0;
        B1.u[1] = hi ? l3 : h1;
        B1.u[2] = hi ? l0 : h2;
        B1.u[3] = hi ? l1 : h3;

        // ---- GEMM1: 2 MFMAs, full 4-term split via k-embedding ----
        f32x16 D1 = {};
        D1 = __builtin_amdgcn_mfma_f32_32x32x16_bf16(A1f1.s, B1.s, D1, 0, 0, 0);
        D1 = __builtin_amdgcn_mfma_f32_32x32x16_bf16(A1f2.s, B1.s, D1, 0, 0, 0);

        // ---- elementwise: r2' = D1 + bb/mu^2 + zz/mu^2 (both fp32) ; w = rsq = mu/r ----
        float wv[16];
        #pragma unroll
        for (int r = 0; r < 16; ++r) {
            float r2 = fmaf(zz, imv[r], D1[r] + bbt[r]);
            wv[r] = __builtin_amdgcn_rsqf(r2);
        }
        float t0 = wv[0] + wv[1],   t1 = wv[2] + wv[3],   t2 = wv[4] + wv[5],   t3 = wv[6] + wv[7];
        float t4 = wv[8] + wv[9],   t5 = wv[10] + wv[11], t6 = wv[12] + wv[13], t7 = wv[14] + wv[15];
        float n_half = ((t0 + t1) + (t2 + t3)) + ((t4 + t5) + (t6 + t7));
        float w3v[16];
        #pragma unroll
        for (int r = 0; r < 16; ++r) w3v[r] = (wv[r] * wv[r]) * wv[r];

        // ---- B2 pack: pure local, hi + lo residual (r14-exact) ----
        FragU B2c0h, B2c1h, B2c0l, B2c1l;
        #pragma unroll
        for (int j = 0; j < 4; ++j) {
            float a = w3v[2 * j], b = w3v[2 * j + 1];
            uint32_t ph = pkbf16(a, b);
            B2c0h.u[j] = ph;
            B2c0l.u[j] = pkbf16(a - lo16f(ph), b - hi16f(ph));
        }
        #pragma unroll
        for (int j = 0; j < 4; ++j) {
            float a = w3v[8 + 2 * j], b = w3v[8 + 2 * j + 1];
            uint32_t ph = pkbf16(a, b);
            B2c1h.u[j] = ph;
            B2c1l.u[j] = pkbf16(a - lo16f(ph), b - hi16f(ph));
        }

        // ---- GEMM2: two INDEPENDENT 4-chains (chunk0 / chunk1), fp32 merge of used elems ----
        f32x16 D2a = {}, D2b = {};
        D2a = __builtin_amdgcn_mfma_f32_32x32x16_bf16(A2h0.s, B2c0h.s, D2a, 0, 0, 0);
        D2b = __builtin_amdgcn_mfma_f32_32x32x16_bf16(A2h1.s, B2c1h.s, D2b, 0, 0, 0);
        D2a = __builtin_amdgcn_mfma_f32_32x32x16_bf16(A2l0.s, B2c0h.s, D2a, 0, 0, 0);
        D2b = __builtin_amdgcn_mfma_f32_32x32x16_bf16(A2l1.s, B2c1h.s, D2b, 0, 0, 0);
        D2a = __builtin_amdgcn_mfma_f32_32x32x16_bf16(A2h0.s, B2c0l.s, D2a, 0, 0, 0);
        D2b = __builtin_amdgcn_mfma_f32_32x32x16_bf16(A2h1.s, B2c1l.s, D2b, 0, 0, 0);
        D2a = __builtin_amdgcn_mfma_f32_32x32x16_bf16(A2l0.s, B2c0l.s, D2a, 0, 0, 0);
        D2b = __builtin_amdgcn_mfma_f32_32x32x16_bf16(A2l1.s, B2c1l.s, D2b, 0, 0, 0);

        // ---- epilogue ----
        float n  = 1.0f + n_half + sx32(n_half);
        float swp = D2a[4] + D2b[4];          // hi0: row8 = sw ; hi1: row12 = 0
        float sw = swp + sx32(swp);
        float scale = DTB * __builtin_amdgcn_rcpf(n);

        float g0 = fmaf(-sw, za0, D2a[0] + D2b[0]);
        float g1 = fmaf(-sw, za1, D2a[1] + D2b[1]);
        float g2 = fmaf(-sw, za2, D2a[2] + D2b[2]);
        float g3 = fmaf(-sw, za3, D2a[3] + D2b[3]);
        za0 = fminf(fmaxf(fmaf(scale, g0, za0), -CLAMPV), CLAMPV);
        za1 = fminf(fmaxf(fmaf(scale, g1, za1), -CLAMPV), CLAMPV);
        za2 = fminf(fmaxf(fmaf(scale, g2, za2), -CLAMPV), CLAMPV);
        za3 = fminf(fmaxf(fmaf(scale, g3, za3), -CLAMPV), CLAMPV);
        zb0 = sx32(za0); zb1 = sx32(za1); zb2 = sx32(za2); zb3 = sx32(za3);
    }

    float4* op = (float4*)out;
    op[(size_t)point * 2 + hi] = make_float4(za0, za1, za2, za3);
}

extern "C" void kernel_launch(void* const* d_in, const int* in_sizes, int n_in,
                              void* d_out, int out_size, void* d_ws, size_t ws_size,
                              hipStream_t stream) {
    const float* z       = (const float*)d_in[0];
    const float* centers = (const float*)d_in[1];
    const float* mus     = (const float*)d_in[2];
    float* out           = (float*)d_out;
    uint4* wsu           = (uint4*)d_ws;

    prep_kernel<<<1, 64, 0, stream>>>(centers, mus, wsu);
    pm_kernel<<<NB / 128, 256, 0, stream>>>(z, wsu, out);   // 4096 blocks, 32 pts/wave
}